// Round 1
// baseline (945.325 us; speedup 1.0000x reference)
//
#include <hip/hip_runtime.h>
#include <math.h>

#define Bb 512
#define Tt 512
#define Kk 128
#define NSTART 126   // K-2
#define NSTOP  127   // K-1

static constexpr float LOG2E = 1.4426950408889634f;
static constexpr float LN2   = 0.6931471805599453f;

__device__ __forceinline__ float fexp2(float x) {
#if __has_builtin(__builtin_amdgcn_exp2f)
  return __builtin_amdgcn_exp2f(x);
#else
  return exp2f(x);
#endif
}
__device__ __forceinline__ float flog2(float x) {
#if __has_builtin(__builtin_amdgcn_logf)
  return __builtin_amdgcn_logf(x);   // v_log_f32 = log2
#else
  return log2f(x);
#endif
}

// One block per batch row. 128 threads = one "next" state each.
// State alpha kept in LDS in log2 units, renormalized (block max -> 0)
// every 4 steps; running offset C2 carried per-thread (uniform).
__global__ __launch_bounds__(128, 1) void crf_nll_kernel(
    const float* __restrict__ feats,   // [B,T,K]
    const int*   __restrict__ tags,    // [B,T]
    const float* __restrict__ trans,   // [K,K]  (trans[next, prev])
    float* __restrict__ part)          // [B] partial (fwd - gold)
{
  const int b = blockIdx.x;
  const int n = threadIdx.x;  // next-state index

  __shared__ float aS[Kk];    // (alpha * log2e) - C2, block-normalized
  __shared__ float red[2];

  // Transition row for this "next" state, pre-scaled to log2 units, in VGPRs.
  float treg[Kk];
  #pragma unroll
  for (int p = 0; p < Kk; ++p)
    treg[p] = trans[n * Kk + p] * LOG2E;

  aS[n] = (n == NSTART) ? 0.0f : (-10000.0f * LOG2E);
  __syncthreads();

  const float* fb = feats + (size_t)b * Tt * Kk;
  float C2 = 0.0f;            // accumulated normalization, log2 units
  float fcur = fb[n];         // feat for t=0 (prefetched)

  for (int t = 0; t < Tt; ++t) {
    // prefetch next step's feat early so HBM latency hides under compute
    float fnext = (t + 1 < Tt) ? fb[(size_t)(t + 1) * Kk + n] : 0.0f;

    float s0 = 0.f, s1 = 0.f, s2 = 0.f, s3 = 0.f;
    float s4 = 0.f, s5 = 0.f, s6 = 0.f, s7 = 0.f;
    #pragma unroll
    for (int p = 0; p < Kk; p += 8) {
      s0 += fexp2(aS[p + 0] + treg[p + 0]);
      s1 += fexp2(aS[p + 1] + treg[p + 1]);
      s2 += fexp2(aS[p + 2] + treg[p + 2]);
      s3 += fexp2(aS[p + 3] + treg[p + 3]);
      s4 += fexp2(aS[p + 4] + treg[p + 4]);
      s5 += fexp2(aS[p + 5] + treg[p + 5]);
      s6 += fexp2(aS[p + 6] + treg[p + 6]);
      s7 += fexp2(aS[p + 7] + treg[p + 7]);
    }
    float s = ((s0 + s1) + (s2 + s3)) + ((s4 + s5) + (s6 + s7));
    // new alpha (log2 units, relative to C2); -inf OK (START row: s==0)
    float y = fcur * LOG2E + flog2(s);

    __syncthreads();                    // all threads done reading aS
    if ((t & 3) == 3) {                 // periodic renormalization
      float m = y;
      #pragma unroll
      for (int off = 32; off >= 1; off >>= 1)
        m = fmaxf(m, __shfl_xor(m, off, 64));
      if ((n & 63) == 0) red[n >> 6] = m;
      __syncthreads();
      m = fmaxf(red[0], red[1]);        // block max (finite; START is -inf but others finite)
      C2 += m;
      aS[n] = y - m;
    } else {
      aS[n] = y;
    }
    __syncthreads();                    // writes visible before next reads
    fcur = fnext;
  }

  // ---- final: forward = ln( sum_n exp(alpha[n] + T[STOP, n]) ) ----
  float tstop = trans[NSTOP * Kk + n] * LOG2E;
  float e = fexp2(aS[n] + tstop);
  #pragma unroll
  for (int off = 32; off >= 1; off >>= 1)
    e += __shfl_xor(e, off, 64);
  if ((n & 63) == 0) red[n >> 6] = e;
  __syncthreads();
  float S = red[0] + red[1];
  float fwd = LN2 * (C2 + flog2(S));    // back to natural log

  // ---- gold path score ----
  const int* tg = tags + (size_t)b * Tt;
  float g = 0.0f;
  for (int t = n; t < Tt; t += Kk) {
    int cur = tg[t];
    int prv = (t == 0) ? NSTART : tg[t - 1];
    g += trans[cur * Kk + prv] + fb[(size_t)t * Kk + cur];
  }
  if (n == 0) g += trans[NSTOP * Kk + tg[Tt - 1]];
  #pragma unroll
  for (int off = 32; off >= 1; off >>= 1)
    g += __shfl_xor(g, off, 64);
  __syncthreads();                      // guard red reuse
  if ((n & 63) == 0) red[n >> 6] = g;
  __syncthreads();
  float gold = red[0] + red[1];

  if (n == 0) part[b] = fwd - gold;
}

__global__ __launch_bounds__(256) void reduce_mean_kernel(
    const float* __restrict__ part, float* __restrict__ out)
{
  __shared__ float buf[4];
  const int tid = threadIdx.x;
  float v = part[tid] + part[tid + 256];
  #pragma unroll
  for (int off = 32; off >= 1; off >>= 1)
    v += __shfl_xor(v, off, 64);
  if ((tid & 63) == 0) buf[tid >> 6] = v;
  __syncthreads();
  if (tid == 0)
    out[0] = (buf[0] + buf[1] + buf[2] + buf[3]) * (1.0f / (float)Bb);
}

extern "C" void kernel_launch(void* const* d_in, const int* in_sizes, int n_in,
                              void* d_out, int out_size, void* d_ws, size_t ws_size,
                              hipStream_t stream) {
  const float* feats = (const float*)d_in[0];
  const int*   tags  = (const int*)d_in[1];
  const float* trans = (const float*)d_in[2];
  float* part = (float*)d_ws;           // 512 floats of scratch

  crf_nll_kernel<<<dim3(Bb), dim3(Kk), 0, stream>>>(feats, tags, trans, part);
  reduce_mean_kernel<<<dim3(1), dim3(256), 0, stream>>>(part, (float*)d_out);
}

// Round 2
// 311.608 us; speedup vs baseline: 3.0337x; 3.0337x over previous
//
#include <hip/hip_runtime.h>
#include <math.h>

#define Bb 512
#define Tt 512
#define Kk 128
#define NSTART 126   // K-2
#define NSTOP  127   // K-1
#define QS 4         // prev-state split factor
#define PW (Kk/QS)   // 32 prev states per thread
#define NTHR (Kk*QS) // 512 threads
#define NWAVE (NTHR/64)

static constexpr float LOG2E = 1.4426950408889634f;
static constexpr float LN2   = 0.6931471805599453f;

__device__ __forceinline__ float fexp2(float x) {
#if __has_builtin(__builtin_amdgcn_exp2f)
  return __builtin_amdgcn_exp2f(x);
#else
  return exp2f(x);
#endif
}
__device__ __forceinline__ float flog2(float x) {
#if __has_builtin(__builtin_amdgcn_logf)
  return __builtin_amdgcn_logf(x);   // v_log_f32 = log2
#else
  return log2f(x);
#endif
}

// One block per batch row; 512 threads = (next-state n = tid>>2, prev-quarter q = tid&3).
// Linear-space forward recursion: a_new[n] = exp(feat[n]) * sum_p E[n,p]*a[p],
// E = exp(trans) held in registers (32 per thread). Alpha in LDS, double-buffered,
// 4 rotation-swizzled copies (copy q rotated by 8q words) => conflict-free b128
// broadcast reads AND 2-way (free) writes. Renormalize block max -> 1 every 4 steps
// (worst-case growth per step <= 128*e^4.5*e^5.5 ~ 1.7e6; 4 steps ~ 8e24 < fp32 max).
__global__ __launch_bounds__(NTHR, 4) void crf_nll_lin(
    const float* __restrict__ feats,   // [B,T,K]
    const int*   __restrict__ tags,    // [B,T]
    const float* __restrict__ trans,   // [K,K]  trans[next, prev]
    float* __restrict__ part)          // [B]
{
  const int b   = blockIdx.x;
  const int tid = threadIdx.x;
  const int n   = tid >> 2;
  const int q   = tid & 3;
  const int w   = tid >> 6;

  __shared__ __align__(16) float aL[2][QS][Kk];
  __shared__ float red[NWAVE];

  // E chunk: exp(trans[n, q*32 .. q*32+31]) in VGPRs
  float E[PW];
  {
    const float4* tr = (const float4*)(trans + (size_t)n * Kk + q * PW);
    #pragma unroll
    for (int j4 = 0; j4 < PW / 4; ++j4) {
      float4 v = tr[j4];
      E[4*j4+0] = fexp2(v.x * LOG2E);
      E[4*j4+1] = fexp2(v.y * LOG2E);
      E[4*j4+2] = fexp2(v.z * LOG2E);
      E[4*j4+3] = fexp2(v.w * LOG2E);
    }
  }

  // alpha0 (linear): 1 at START, 0 elsewhere; into buf0, all rotated copies
  aL[0][q][(n + 8*q) & (Kk-1)] = (n == NSTART) ? 1.0f : 0.0f;
  __syncthreads();

  const float* fb = feats + (size_t)b * Tt * Kk;
  float C2   = 0.0f;          // accumulated renorm offset, log2 units (uniform)
  float fcur = fb[n];         // feat for t=0

  for (int t = 0; t < Tt; ++t) {
    const int cur = t & 1, nxt = cur ^ 1;
    float fnext = (t + 1 < Tt) ? fb[(size_t)(t + 1) * Kk + n] : 0.0f;

    // partial dot over this thread's 32 prev states (conflict-free b128 broadcasts)
    const float* ap = &aL[cur][q][0];
    float s0 = 0.f, s1 = 0.f, s2 = 0.f, s3 = 0.f;
    #pragma unroll
    for (int j = 0; j < PW; j += 4) {
      const int wrd = (q * PW + j + 8 * q) & (Kk - 1);   // loop-invariant-hoistable
      const float4 av = *(const float4*)(ap + wrd);
      s0 = fmaf(E[j+0], av.x, s0);
      s1 = fmaf(E[j+1], av.y, s1);
      s2 = fmaf(E[j+2], av.z, s2);
      s3 = fmaf(E[j+3], av.w, s3);
    }
    float s = (s0 + s1) + (s2 + s3);
    s += __shfl_xor(s, 1, 64);          // combine the 4 q-partials (lanes share n)
    s += __shfl_xor(s, 2, 64);
    float y = fexp2(fcur * LOG2E) * s;  // * exp(feat[t,n])

    if ((t & 3) == 3) {                 // renormalize: block max -> 1
      float m = y;
      m = fmaxf(m, __shfl_xor(m, 4, 64));
      m = fmaxf(m, __shfl_xor(m, 8, 64));
      m = fmaxf(m, __shfl_xor(m, 16, 64));
      m = fmaxf(m, __shfl_xor(m, 32, 64));
      if ((tid & 63) == 0) red[w] = m;
      __syncthreads();
      m = red[0];
      #pragma unroll
      for (int i = 1; i < NWAVE; ++i) m = fmaxf(m, red[i]);
      C2 += flog2(m);
      y *= (1.0f / m);
    }
    aL[nxt][q][(n + 8*q) & (Kk-1)] = y;
    __syncthreads();                    // writes visible; prev-buffer reads done
    fcur = fnext;
  }

  // ---- forward score: ln( sum_n a[n] * exp(T[STOP,n]) ) + renorm offset ----
  float estop = fexp2(trans[(size_t)NSTOP * Kk + n] * LOG2E);  // exp(-1e4) -> 0, fine
  float v = (q == 0) ? aL[0][0][n] * estop : 0.0f;  // final alpha is in buf0, copy0
  #pragma unroll
  for (int off = 32; off >= 1; off >>= 1) v += __shfl_xor(v, off, 64);
  if ((tid & 63) == 0) red[w] = v;
  __syncthreads();
  float S = red[0];
  #pragma unroll
  for (int i = 1; i < NWAVE; ++i) S += red[i];
  const float fwd = LN2 * (C2 + flog2(S));

  // ---- gold path score (one timestep per thread; Tt == NTHR) ----
  __syncthreads();                      // red reuse guard
  const int* tg = tags + (size_t)b * Tt;
  int curt = tg[tid];
  int prv  = (tid == 0) ? NSTART : tg[tid - 1];
  float g = trans[(size_t)curt * Kk + prv] + fb[(size_t)tid * Kk + curt];
  if (tid == 0) g += trans[(size_t)NSTOP * Kk + tg[Tt - 1]];
  #pragma unroll
  for (int off = 32; off >= 1; off >>= 1) g += __shfl_xor(g, off, 64);
  if ((tid & 63) == 0) red[w] = g;
  __syncthreads();
  float gold = red[0];
  #pragma unroll
  for (int i = 1; i < NWAVE; ++i) gold += red[i];

  if (tid == 0) part[b] = fwd - gold;
}

__global__ __launch_bounds__(256) void reduce_mean_kernel(
    const float* __restrict__ part, float* __restrict__ out)
{
  __shared__ float buf[4];
  const int tid = threadIdx.x;
  float v = part[tid] + part[tid + 256];
  #pragma unroll
  for (int off = 32; off >= 1; off >>= 1) v += __shfl_xor(v, off, 64);
  if ((tid & 63) == 0) buf[tid >> 6] = v;
  __syncthreads();
  if (tid == 0)
    out[0] = (buf[0] + buf[1] + buf[2] + buf[3]) * (1.0f / (float)Bb);
}

extern "C" void kernel_launch(void* const* d_in, const int* in_sizes, int n_in,
                              void* d_out, int out_size, void* d_ws, size_t ws_size,
                              hipStream_t stream) {
  const float* feats = (const float*)d_in[0];
  const int*   tags  = (const int*)d_in[1];
  const float* trans = (const float*)d_in[2];
  float* part = (float*)d_ws;

  crf_nll_lin<<<dim3(Bb), dim3(NTHR), 0, stream>>>(feats, tags, trans, part);
  reduce_mean_kernel<<<dim3(1), dim3(256), 0, stream>>>(part, (float*)d_out);
}

// Round 3
// 256.508 us; speedup vs baseline: 3.6854x; 1.2148x over previous
//
#include <hip/hip_runtime.h>
#include <math.h>

#define Bb 512
#define Tt 512
#define Kk 128
#define NSTART 126   // K-2
#define NSTOP  127   // K-1
#define PW 32        // prev states per thread (quarter)
#define NTHR 256     // threads per block

static constexpr float LOG2E = 1.4426950408889634f;
static constexpr float LN2   = 0.6931471805599453f;

__device__ __forceinline__ float fexp2(float x) {
  return __builtin_amdgcn_exp2f(x);
}
__device__ __forceinline__ float flog2(float x) {
  return __builtin_amdgcn_logf(x);   // v_log_f32 = log2
}

// One block per batch row; 256 threads: q = tid&3 (prev-quarter, 32 states),
// nb = tid>>2 (0..63) -> this thread produces next-states nb and nb+64.
// Linear-space recursion a_new[n] = exp(feat[n]) * sum_p E[n,p] a[p].
// E rows (exp(trans), fp32) pinned in VGPRs via asm liveness barrier (64 regs).
// Alpha: LDS, double-buffered, 4 rotated copies: copy q stores alpha[p] at
// word (p - 8q) & 127, so thread reads words q*24 + j (no wrap, banks
// {0,8,16,24}+j disjoint across q => conflict-free b128 broadcasts).
// Renormalize block max -> 1 every 4 steps (worst-case growth ~2e6/step,
// 4 steps ~1.6e25 << fp32 max).
__global__ __launch_bounds__(NTHR, 2) void crf_nll_lin2(
    const float* __restrict__ feats,   // [B,T,K]
    const int*   __restrict__ tags,    // [B,T]
    const float* __restrict__ trans,   // [K,K]  trans[next, prev]
    float* __restrict__ part)          // [B]
{
  const int b   = blockIdx.x;
  const int tid = threadIdx.x;
  const int q   = tid & 3;
  const int nb  = tid >> 2;       // 0..63
  const int n0  = nb;
  const int n1  = nb + 64;
  const int w   = tid >> 6;       // wave id 0..3

  __shared__ __align__(16) float aL[2][4][Kk];
  __shared__ float red[4];

  // ---- E rows in registers (exp of transitions), pinned ----
  float E0[PW], E1[PW];
  {
    const float* t0 = trans + (size_t)n0 * Kk + q * PW;
    const float* t1 = trans + (size_t)n1 * Kk + q * PW;
    #pragma unroll
    for (int j = 0; j < PW; j += 4) {
      float4 v0 = *(const float4*)(t0 + j);
      float4 v1 = *(const float4*)(t1 + j);
      E0[j+0] = fexp2(v0.x * LOG2E);
      E0[j+1] = fexp2(v0.y * LOG2E);
      E0[j+2] = fexp2(v0.z * LOG2E);
      E0[j+3] = fexp2(v0.w * LOG2E);
      E1[j+0] = fexp2(v1.x * LOG2E);
      E1[j+1] = fexp2(v1.y * LOG2E);
      E1[j+2] = fexp2(v1.z * LOG2E);
      E1[j+3] = fexp2(v1.w * LOG2E);
    }
  }
  #pragma unroll
  for (int j = 0; j < PW; ++j) {
    asm volatile("" : "+v"(E0[j]), "+v"(E1[j]));   // forbid rematerialization
  }

  // ---- alpha0 (linear): 1 at START, 0 elsewhere; into buf0, all copies ----
  aL[0][q][(n0 - 8*q) & (Kk-1)] = (n0 == NSTART) ? 1.0f : 0.0f;
  aL[0][q][(n1 - 8*q) & (Kk-1)] = (n1 == NSTART) ? 1.0f : 0.0f;
  __syncthreads();

  const float* fb = feats + (size_t)b * Tt * Kk;
  float C2 = 0.0f;                 // renorm offset, log2 units (uniform)
  float f0 = fb[n0], f1 = fb[n1];  // feats for t=0

  for (int t = 0; t < Tt; ++t) {
    const int cur = t & 1;
    float f0n = 0.f, f1n = 0.f;
    if (t + 1 < Tt) {              // prefetch next step's feats
      f0n = fb[(size_t)(t + 1) * Kk + n0];
      f1n = fb[(size_t)(t + 1) * Kk + n1];
    }

    // 8 conflict-free b128 broadcast reads serve 64 fma (2 rows)
    const float* ap = &aL[cur][q][q * 24];
    float a0=0.f,a1=0.f,a2=0.f,a3=0.f, c0=0.f,c1=0.f,c2=0.f,c3=0.f;
    #pragma unroll
    for (int j4 = 0; j4 < PW/4; ++j4) {
      const float4 av = *(const float4*)(ap + j4*4);
      a0 = fmaf(E0[4*j4+0], av.x, a0);
      a1 = fmaf(E0[4*j4+1], av.y, a1);
      a2 = fmaf(E0[4*j4+2], av.z, a2);
      a3 = fmaf(E0[4*j4+3], av.w, a3);
      c0 = fmaf(E1[4*j4+0], av.x, c0);
      c1 = fmaf(E1[4*j4+1], av.y, c1);
      c2 = fmaf(E1[4*j4+2], av.z, c2);
      c3 = fmaf(E1[4*j4+3], av.w, c3);
    }
    float s0 = (a0 + a1) + (a2 + a3);
    float s1 = (c0 + c1) + (c2 + c3);
    s0 += __shfl_xor(s0, 1, 64);     // combine q-quad
    s0 += __shfl_xor(s0, 2, 64);
    s1 += __shfl_xor(s1, 1, 64);
    s1 += __shfl_xor(s1, 2, 64);
    float y0 = fexp2(f0 * LOG2E) * s0;
    float y1 = fexp2(f1 * LOG2E) * s1;

    if ((t & 3) == 3) {              // renormalize block max -> 1
      float m = fmaxf(y0, y1);
      m = fmaxf(m, __shfl_xor(m, 4, 64));
      m = fmaxf(m, __shfl_xor(m, 8, 64));
      m = fmaxf(m, __shfl_xor(m, 16, 64));
      m = fmaxf(m, __shfl_xor(m, 32, 64));
      if ((tid & 63) == 0) red[w] = m;
      __syncthreads();
      m = fmaxf(fmaxf(red[0], red[1]), fmaxf(red[2], red[3]));
      C2 += flog2(m);
      float inv = 1.0f / m;
      y0 *= inv; y1 *= inv;
    }

    const int nxt = cur ^ 1;
    aL[nxt][q][(n0 - 8*q) & (Kk-1)] = y0;
    aL[nxt][q][(n1 - 8*q) & (Kk-1)] = y1;
    __syncthreads();
    f0 = f0n; f1 = f1n;
  }

  // ---- forward score: ln( sum_n a[n] * exp(T[STOP,n]) ) + offset ----
  // final alpha is in buf 0 (512 steps), copy 0 has rotation 0.
  float v = 0.0f;
  if (tid < Kk) {
    float es = fexp2(trans[(size_t)NSTOP * Kk + tid] * LOG2E);
    v = aL[0][0][tid] * es;
  }
  #pragma unroll
  for (int off = 32; off >= 1; off >>= 1) v += __shfl_xor(v, off, 64);
  if ((tid & 63) == 0) red[w] = v;
  __syncthreads();
  const float S = (red[0] + red[1]) + (red[2] + red[3]);
  const float fwd = LN2 * (C2 + flog2(S));

  // ---- gold path score (2 timesteps per thread) ----
  __syncthreads();                   // red reuse guard
  const int* tg = tags + (size_t)b * Tt;
  float g = 0.0f;
  #pragma unroll
  for (int k2 = 0; k2 < Tt / NTHR; ++k2) {
    const int tt  = tid + k2 * NTHR;
    const int curt = tg[tt];
    const int prv  = (tt == 0) ? NSTART : tg[tt - 1];
    g += trans[(size_t)curt * Kk + prv] + fb[(size_t)tt * Kk + curt];
  }
  if (tid == 0) g += trans[(size_t)NSTOP * Kk + tg[Tt - 1]];
  #pragma unroll
  for (int off = 32; off >= 1; off >>= 1) g += __shfl_xor(g, off, 64);
  if ((tid & 63) == 0) red[w] = g;
  __syncthreads();
  const float gold = (red[0] + red[1]) + (red[2] + red[3]);

  if (tid == 0) part[b] = fwd - gold;
}

__global__ __launch_bounds__(256) void reduce_mean_kernel(
    const float* __restrict__ part, float* __restrict__ out)
{
  __shared__ float buf[4];
  const int tid = threadIdx.x;
  float v = part[tid] + part[tid + 256];
  #pragma unroll
  for (int off = 32; off >= 1; off >>= 1) v += __shfl_xor(v, off, 64);
  if ((tid & 63) == 0) buf[tid >> 6] = v;
  __syncthreads();
  if (tid == 0)
    out[0] = (buf[0] + buf[1] + buf[2] + buf[3]) * (1.0f / (float)Bb);
}

extern "C" void kernel_launch(void* const* d_in, const int* in_sizes, int n_in,
                              void* d_out, int out_size, void* d_ws, size_t ws_size,
                              hipStream_t stream) {
  const float* feats = (const float*)d_in[0];
  const int*   tags  = (const int*)d_in[1];
  const float* trans = (const float*)d_in[2];
  float* part = (float*)d_ws;

  crf_nll_lin2<<<dim3(Bb), dim3(NTHR), 0, stream>>>(feats, tags, trans, part);
  reduce_mean_kernel<<<dim3(1), dim3(256), 0, stream>>>(part, (float*)d_out);
}